// Round 9
// baseline (78.841 us; speedup 1.0000x reference)
//
#include <hip/hip_runtime.h>
#include <hip/hip_bf16.h>
#include <math.h>

// FluxHead: B=4, T=4096, D_MODEL=1024, HEAD_DIM=128, STRIDE=4, Tk=1024, CAUSAL
// Exact-math simplifications:
//  - spectral gate adds a per-(b,q) scalar to logits -> softmax-invariant -> skipped
//  - reverse branch == unmasked forward attention, output read at mirror row
//  - pooling commutes with K/V projection -> pooled in GEMM epilogue (lane-local)
//  - log2e/SCALE folded into Wq -> softmax in exp2 units

#define T_ 4096
#define TK_ 1024

typedef __attribute__((ext_vector_type(8))) short bf16x8;
typedef __attribute__((ext_vector_type(4))) float f32x4;
typedef __attribute__((ext_vector_type(4))) short s16x4;
typedef __attribute__((address_space(1))) unsigned int gas_u32;
typedef __attribute__((address_space(3))) unsigned int las_u32;

__device__ inline short f2bf(float f) {
  unsigned u = __builtin_bit_cast(unsigned, f);
  u = (u + 0x7FFFu + ((u >> 16) & 1u)) >> 16;
  return (short)u;
}
__device__ inline f32x4 mfma16(bf16x8 a, bf16x8 b, f32x4 c) {
  return __builtin_amdgcn_mfma_f32_16x16x32_bf16(a, b, c, 0, 0, 0);
}
__device__ inline void gll16(const void* g, void* l) {
  __builtin_amdgcn_global_load_lds((gas_u32*)g, (las_u32*)l, 16, 0, 0);
}
#define VMCNT(n) asm volatile("s_waitcnt vmcnt(" #n ")" ::: "memory")

// ---- rope table: cos/sin[t][d], t<4096, d<64 ----
__global__ __launch_bounds__(256) void rope_kernel(float* __restrict__ cosT,
                                                   float* __restrict__ sinT) {
  int i = blockIdx.x * 256 + threadIdx.x;  // 262144
  int t = i >> 6, d = i & 63;
  float theta = powf(10000.f, -(float)d * (1.f / 64.f));
  float fr = (float)t * theta;
  cosT[i] = cosf(fr);
  sinT[i] = sinf(fr);
}

// ---- WT prep: [384][1024] bf16, PRE-SWIZZLED bytes within each 128B k-block:
// byte = ((k&63)*2) ^ ((n&7)<<4). Sections: [0..127]=Wq*scale, [128..255]=Wk,
// [256..383]=Wv. Q/K rows reordered so each wave's 64-col slice holds matched
// rope lo/hi pairs: row n: col = (n>>6)*32 + (n&31) + ((n>>5)&1)*64.
__global__ __launch_bounds__(256) void wtprep_kernel(const float* __restrict__ Wq,
                                                     const float* __restrict__ Wk,
                                                     const float* __restrict__ Wv,
                                                     char* __restrict__ WT) {
  int i = blockIdx.x * 256 + threadIdx.x;  // 384*1024
  int n = i >> 10, k = i & 1023;
  float v;
  if (n < 128) {
    int col = (n >> 6) * 32 + (n & 31) + ((n >> 5) & 1) * 64;
    v = Wq[(size_t)k * 128 + col] * 0.12751741656f;  // log2(e)/sqrt(128)
  } else if (n < 256) {
    int nk = n - 128;
    int col = (nk >> 6) * 32 + (nk & 31) + ((nk >> 5) & 1) * 64;
    v = Wk[(size_t)k * 128 + col];
  } else {
    v = Wv[(size_t)k * 128 + (n - 256)];
  }
  size_t off = (size_t)n * 2048 + (size_t)(k >> 6) * 128 + (((k & 63) * 2) ^ ((n & 7) << 4));
  *(short*)(WT + off) = f2bf(v);
}

// ---- projection GEMM: grid 768 = 8 XCD x (32 M-tiles x 3 N-blocks).
// Trio (same M-tile, 3 N-blocks) co-located on one XCD for x L2 reuse.
// Double-buffered, ONE __syncthreads per K-step (m97 pattern): stage(t+1) +
// AWRITE(t+1) issued before COMPUTE(t); the barrier's full drain lands after
// the MFMA block, so L2 latency is hidden. No raw-asm waits (correct by
// construction).
__global__ __launch_bounds__(256, 3) void gemm_fused(const float* __restrict__ x,
                                                     const char* __restrict__ WT,
                                                     const float* __restrict__ cosT,
                                                     const float* __restrict__ sinT,
                                                     short* __restrict__ Qb,
                                                     char* __restrict__ Kswz,
                                                     char* __restrict__ Vswz) {
  __shared__ __align__(16) char Al[2][8192];    // 64 rows x 64 k bf16, swizzled
  __shared__ __align__(16) char Bl[2][16384];   // 128 rows x 64 k bf16, pre-swz copy
  const int tid = threadIdx.x;
  const int w = tid >> 6, g = (tid >> 4) & 3, c = tid & 15;
  const int wr = w >> 1, wc = w & 1;
  const int swc = (c & 7) << 4;
  // grid decode: trio packing per XCD
  const int x8 = blockIdx.x & 7, jj0 = blockIdx.x >> 3;  // jj0: 0..95
  const int nb = jj0 % 3, tl = jj0 / 3;                  // 32 trios per XCD
  const int mt = x8 * 32 + tl;
  const int m0 = mt * 64;
  const char* WTB = WT + (size_t)nb * 128 * 2048;
  // A staging role
  const int arow = tid >> 2, apart = tid & 3;
  const int sws = (arow & 7) << 4;
  const float* xsrc = x + (size_t)(m0 + arow) * 1024 + apart * 16;

  f32x4 acc[2][4];
#pragma unroll
  for (int mf = 0; mf < 2; mf++)
#pragma unroll
    for (int n = 0; n < 4; n++) acc[mf][n] = (f32x4){0.f, 0.f, 0.f, 0.f};

  float4 areg[4];
  auto ALOAD = [&](int ki) {
#pragma unroll
    for (int t = 0; t < 4; t++) areg[t] = *(const float4*)(xsrc + (size_t)ki * 64 + t * 4);
  };
  auto AWRITE = [&](int buf) {
    bf16x8 v0 = {f2bf(areg[0].x), f2bf(areg[0].y), f2bf(areg[0].z), f2bf(areg[0].w),
                 f2bf(areg[1].x), f2bf(areg[1].y), f2bf(areg[1].z), f2bf(areg[1].w)};
    bf16x8 v1 = {f2bf(areg[2].x), f2bf(areg[2].y), f2bf(areg[2].z), f2bf(areg[2].w),
                 f2bf(areg[3].x), f2bf(areg[3].y), f2bf(areg[3].z), f2bf(areg[3].w)};
    *(bf16x8*)(Al[buf] + arow * 128 + ((apart * 32) ^ sws)) = v0;
    *(bf16x8*)(Al[buf] + arow * 128 + ((apart * 32 + 16) ^ sws)) = v1;
  };
  auto BSTAGE = [&](int ki, int buf) {
#pragma unroll
    for (int i2 = 0; i2 < 4; i2++) {
      int j = tid + 256 * i2;
      gll16(WTB + (size_t)(j >> 3) * 2048 + ki * 128 + (j & 7) * 16, Bl[buf] + j * 16);
    }
  };
  auto COMPUTE = [&](int buf) {
#pragma unroll
    for (int kc = 0; kc < 2; kc++) {
      bf16x8 af[2], bfr[4];
#pragma unroll
      for (int mf = 0; mf < 2; mf++)
        af[mf] = *(const bf16x8*)(Al[buf] + (wr * 32 + mf * 16 + c) * 128 + ((kc * 64 + 16 * g) ^ swc));
#pragma unroll
      for (int n0 = 0; n0 < 4; n0++)
        bfr[n0] = *(const bf16x8*)(Bl[buf] + (wc * 64 + n0 * 16 + c) * 128 + ((kc * 64 + 16 * g) ^ swc));
#pragma unroll
      for (int mf = 0; mf < 2; mf++)
#pragma unroll
        for (int n0 = 0; n0 < 4; n0++) acc[mf][n0] = mfma16(af[mf], bfr[n0], acc[mf][n0]);
    }
  };

  // prologue: tile 0 into buf0; x(1) into regs
  ALOAD(0);
  AWRITE(0);
  BSTAGE(0, 0);
  ALOAD(1);
  __syncthreads();
#pragma unroll 1
  for (int ki = 0; ki < 16; ki++) {
    const int cur = ki & 1;
    if (ki + 1 < 16) {
      AWRITE(cur ^ 1);                          // x(ki+1) regs -> other A buffer
      BSTAGE(ki + 1, cur ^ 1);                  // W(ki+1) -> other B buffer
      ALOAD(ki + 2 < 16 ? ki + 2 : 15);         // x(ki+2) -> regs
    }
    COMPUTE(cur);
    __syncthreads();                            // drain covered by the 16 MFMAs
  }

  // ---- epilogue: acc[mf][n0][r] = C[m0 + wr*32 + mf*16 + 4g + r][wc*64 + n0*16 + c]
  if (nb == 0) {
#pragma unroll
    for (int mf = 0; mf < 2; mf++)
#pragma unroll
      for (int r = 0; r < 4; r++) {
        int mm = m0 + wr * 32 + mf * 16 + 4 * g + r;
        int t = mm & 4095;
#pragma unroll
        for (int n0 = 0; n0 < 2; n0++) {
          int d = wc * 32 + n0 * 16 + c;
          float co = cosT[t * 64 + d], si = sinT[t * 64 + d];
          float lo = acc[mf][n0][r], hi = acc[mf][n0 + 2][r];
          Qb[(size_t)mm * 128 + d] = f2bf(lo * co - hi * si);
          Qb[(size_t)mm * 128 + d + 64] = f2bf(hi * co + lo * si);
        }
      }
  } else if (nb == 1) {
#pragma unroll
    for (int mf = 0; mf < 2; mf++) {
      int kp = ((m0 + wr * 32 + mf * 16) >> 2) + g;
      int kpos = kp & 1023;
      int ksw = (kp & 7) << 4;
      char* kb2 = Kswz + (size_t)kp * 256;
#pragma unroll
      for (int n0 = 0; n0 < 2; n0++) {
        int d = wc * 32 + n0 * 16 + c;
        float lo = 0.25f * (acc[mf][n0][0] + acc[mf][n0][1] + acc[mf][n0][2] + acc[mf][n0][3]);
        float hi = 0.25f * (acc[mf][n0 + 2][0] + acc[mf][n0 + 2][1] + acc[mf][n0 + 2][2] + acc[mf][n0 + 2][3]);
        float co = cosT[kpos * 64 + d], si = sinT[kpos * 64 + d];
        *(short*)(kb2 + ((d * 2) ^ ksw)) = f2bf(lo * co - hi * si);
        *(short*)(kb2 + (((d + 64) * 2) ^ ksw)) = f2bf(hi * co + lo * si);
      }
    }
  } else {
    // V: pool over r, store [b][tile32][64 r][144B]: byte = r*144 + h*64 + kk*2
    // (pitch 144 = 36 banks/row -> bank = (36r+16h+4g)%32, conflict-free reads)
#pragma unroll
    for (int mf = 0; mf < 2; mf++) {
      int kp = ((m0 + wr * 32 + mf * 16) >> 2) + g;
      int kpos = kp & 1023, bb = kp >> 10;
#pragma unroll
      for (int n0 = 0; n0 < 4; n0++) {
        int r = n0 * 16 + c;         // d = wc*64 + r, h = wc
        float vp = 0.25f * (acc[mf][n0][0] + acc[mf][n0][1] + acc[mf][n0][2] + acc[mf][n0][3]);
        size_t off = (size_t)(bb * 32 + (kpos >> 5)) * 9216 + r * 144 + wc * 64 +
                     (kpos & 31) * 2;
        *(short*)(Vswz + off) = f2bf(vp);
      }
    }
  }
}

// ---- fused two-branch flash attention, mirror-paired block, KVBLK=32 ----
// grid 512, 256 thr = 4 waves: w0,w1 causal rows [q0b, q0b+32); w2,w3 unmasked
// mirror rows; combine through LDS; swapped QK^T (lane-local softmax).
// V in pitch-144 rows -> conflict-free PV reads (r8 had 4-way: 3.77M conflicts).
__global__ __launch_bounds__(256, 4) void attn_kernel(const short* __restrict__ Qb,
                                                      const char* __restrict__ Kswz,
                                                      const char* __restrict__ Vswz,
                                                      const float* __restrict__ alphap,
                                                      float* __restrict__ out) {
  __shared__ __align__(16) char lds[16384 + 18432 + 4 * 1280];  // K + V + P = 39936
  char* Kl = lds;            // 2 bufs x [32 keys x 256B] (pre-swz rows)
  char* Vl = lds + 16384;    // 2 bufs x [64 r x 144B]
  const int tid = threadIdx.x;
  const int w = tid >> 6, g = (tid >> 4) & 3, c = tid & 15;
  char* Pl = lds + 34816 + w * 1280;
  const int blk = blockIdx.x;
  const int b = blk >> 7, qc = blk & 127;
  const int q0b = qc * 32;
  const bool isC = (w < 2);
  const int qbase = isC ? (q0b + w * 16) : (4064 - q0b + (w - 2) * 16);
  const int myq = qbase + c;
  const int tile_b = qbase >> 7;  // boundary 32-key tile for this wave
  const int swc = (c & 7) << 4;

  bf16x8 qf[4];
  {
    const short* qr = Qb + ((size_t)b * T_ + myq) * 128;
#pragma unroll
    for (int kc = 0; kc < 4; kc++) qf[kc] = *(const bf16x8*)(qr + kc * 32 + 8 * g);
  }
  f32x4 acc[8];
#pragma unroll
  for (int n = 0; n < 8; n++) acc[n] = (f32x4){0.f, 0.f, 0.f, 0.f};
  float m = -1e30f, l = 0.f;

  const char* kbB = Kswz + (size_t)b * 262144;
  const char* vbB = Vswz + (size_t)b * 294912;

  auto STG = [&](int tg, char* kd, char* vd) {
    const char* kb = kbB + (size_t)tg * 8192;
    const char* vb = vbB + (size_t)tg * 9216;
#pragma unroll
    for (int j = 0; j < 2; j++) gll16(kb + j * 4096 + tid * 16, kd + j * 4096 + tid * 16);
#pragma unroll
    for (int j = 0; j < 2; j++) gll16(vb + j * 4096 + tid * 16, vd + j * 4096 + tid * 16);
    if (tid < 64) gll16(vb + 8192 + tid * 16, vd + 8192 + tid * 16);  // 1KB tail (wave 0)
  };

  STG(0, Kl, Vl);

#pragma unroll 1
  for (int tg = 0; tg < 32; tg++) {
    const int kcur = (tg & 1) * 8192;
    const int vcur = (tg & 1) * 9216;
    if (tg < 31) {
      STG(tg + 1, Kl + (8192 - kcur), Vl + (9216 - vcur));
      if (w == 0) { VMCNT(5); } else { VMCNT(4); }  // drain prev tile; keep newest
    } else {
      VMCNT(0);
    }
    __builtin_amdgcn_s_barrier();

    if (!isC || tg <= tile_b) {
      // QK^T swapped: s[n][r] = S[key = tg*32 + 16n + 4g + r][q = myq]
      f32x4 s[2];
#pragma unroll
      for (int n = 0; n < 2; n++) s[n] = (f32x4){0.f, 0.f, 0.f, 0.f};
#pragma unroll
      for (int kc = 0; kc < 4; kc++) {
#pragma unroll
        for (int n = 0; n < 2; n++) {
          bf16x8 kf = *(const bf16x8*)(Kl + kcur + (16 * n + c) * 256 + ((kc * 64 + 16 * g) ^ swc));
          s[n] = mfma16(kf, qf[kc], s[n]);
        }
      }
      if (isC && tg == tile_b) {  // boundary mask
        int klim = (myq >> 2) - tg * 32;
#pragma unroll
        for (int n = 0; n < 2; n++)
#pragma unroll
          for (int r = 0; r < 4; r++)
            if (16 * n + 4 * g + r > klim) s[n][r] = -3.0e38f;
      }
      float tm = fmaxf(fmaxf(fmaxf(s[0][0], s[0][1]), fmaxf(s[0][2], s[0][3])),
                       fmaxf(fmaxf(s[1][0], s[1][1]), fmaxf(s[1][2], s[1][3])));
      tm = fmaxf(tm, __shfl_xor(tm, 16));
      tm = fmaxf(tm, __shfl_xor(tm, 32));
      if (__any(tm > m + 8.f)) {  // defer-max
        float mn = fmaxf(m, tm);
        float sc = __builtin_amdgcn_exp2f(m - mn);
        m = mn;
        l *= sc;
        float s0 = __shfl(sc, 4 * g), s1 = __shfl(sc, 4 * g + 1);
        float s2 = __shfl(sc, 4 * g + 2), s3 = __shfl(sc, 4 * g + 3);
        f32x4 scv = {s0, s1, s2, s3};
#pragma unroll
        for (int n0 = 0; n0 < 8; n0++) acc[n0] *= scv;
      }
      float rsum = 0.f;
#pragma unroll
      for (int n = 0; n < 2; n++) {
        float p0 = __builtin_amdgcn_exp2f(s[n][0] - m);
        float p1 = __builtin_amdgcn_exp2f(s[n][1] - m);
        float p2 = __builtin_amdgcn_exp2f(s[n][2] - m);
        float p3 = __builtin_amdgcn_exp2f(s[n][3] - m);
        rsum += (p0 + p1) + (p2 + p3);
        s16x4 pk = {f2bf(p0), f2bf(p1), f2bf(p2), f2bf(p3)};
        *(s16x4*)(Pl + c * 80 + 32 * n + 8 * g) = pk;
      }
      rsum += __shfl_xor(rsum, 16);
      rsum += __shfl_xor(rsum, 32);
      l += rsum;
      bf16x8 pf0 = *(const bf16x8*)(Pl + c * 80 + 16 * g);
#pragma unroll
      for (int n0 = 0; n0 < 8; n0++) {
        // V row r = (n0&3)*16 + c, half h = n0>>2, keys 8g..8g+7
        bf16x8 v0 = *(const bf16x8*)(Vl + vcur + ((n0 & 3) * 16 + c) * 144 + (n0 >> 2) * 64 + 16 * g);
        acc[n0] = mfma16(pf0, v0, acc[n0]);
      }
    }
    __builtin_amdgcn_s_barrier();
  }

  // epilogue: per-output-row 1/l, exchange U through LDS, combine, write
  float lr0 = __shfl(l, 4 * g), lr1 = __shfl(l, 4 * g + 1);
  float lr2 = __shfl(l, 4 * g + 2), lr3 = __shfl(l, 4 * g + 3);
  f32x4 linv = {1.f / lr0, 1.f / lr1, 1.f / lr2, 1.f / lr3};
  float* Ul = (float*)lds;  // [32][132] overlay = 16.9 KB (all K/V reads done)
  if (!isC) {
#pragma unroll
    for (int n0 = 0; n0 < 8; n0++)
#pragma unroll
      for (int r = 0; r < 4; r++) {
        int urow = 31 - (16 * (w - 2) + 4 * g + r);
        Ul[urow * 132 + n0 * 16 + c] = acc[n0][r] * linv[r];
      }
  }
  __syncthreads();
  if (isC) {
    float alpha = 1.f / (1.f + expf(-alphap[0]));
    float oma = 1.f - alpha;
#pragma unroll
    for (int n0 = 0; n0 < 8; n0++)
#pragma unroll
      for (int r = 0; r < 4; r++) {
        int j = 16 * w + 4 * g + r;
        float uvv = Ul[j * 132 + n0 * 16 + c];
        out[((size_t)b * T_ + q0b + j) * 128 + n0 * 16 + c] =
            alpha * acc[n0][r] * linv[r] + oma * uvv;
      }
  }
}

extern "C" void kernel_launch(void* const* d_in, const int* in_sizes, int n_in,
                              void* d_out, int out_size, void* d_ws, size_t ws_size,
                              hipStream_t stream) {
  const float* x = (const float*)d_in[0];
  const float* Wq = (const float*)d_in[1];
  const float* Wk = (const float*)d_in[2];
  const float* Wv = (const float*)d_in[3];
  const float* falpha = (const float*)d_in[9];
  char* ws = (char*)d_ws;
  float* cosT = (float*)(ws);                  // 1 MB
  float* sinT = (float*)(ws + 1048576);        // 1 MB
  char* WT = ws + 2097152;                     // 768 KB  [384][1024] bf16, pre-swizzled
  short* Qb = (short*)(ws + 2883584);          // 4 MB    roped+scaled Q bf16
  char* Kswz = ws + 7077888;                   // 1 MB    roped pooled K bf16, swizzled
  char* Vswz = ws + 8126464;                   // 1.18 MB pooled V, [b][tile32][64r][144B]

  rope_kernel<<<1024, 256, 0, stream>>>(cosT, sinT);
  wtprep_kernel<<<1536, 256, 0, stream>>>(Wq, Wk, Wv, WT);
  gemm_fused<<<768, 256, 0, stream>>>(x, WT, cosT, sinT, Qb, Kswz, Vswz);
  attn_kernel<<<512, 256, 0, stream>>>(Qb, Kswz, Vswz, falpha, (float*)d_out);
}

// Round 10
// 74.981 us; speedup vs baseline: 1.0515x; 1.0515x over previous
//
#include <hip/hip_runtime.h>
#include <hip/hip_bf16.h>
#include <math.h>

// FluxHead: B=4, T=4096, D_MODEL=1024, HEAD_DIM=128, STRIDE=4, Tk=1024, CAUSAL
// Exact-math simplifications:
//  - spectral gate adds a per-(b,q) scalar to logits -> softmax-invariant -> skipped
//  - reverse branch == unmasked forward attention, output read at mirror row
//  - pooling commutes with K/V projection -> pooled in GEMM epilogue (lane-local)
//  - log2e/SCALE folded into Wq -> softmax in exp2 units

#define T_ 4096
#define TK_ 1024

typedef __attribute__((ext_vector_type(8))) short bf16x8;
typedef __attribute__((ext_vector_type(4))) float f32x4;
typedef __attribute__((ext_vector_type(4))) short s16x4;
typedef __attribute__((address_space(1))) unsigned int gas_u32;
typedef __attribute__((address_space(3))) unsigned int las_u32;

__device__ inline short f2bf(float f) {
  unsigned u = __builtin_bit_cast(unsigned, f);
  u = (u + 0x7FFFu + ((u >> 16) & 1u)) >> 16;
  return (short)u;
}
__device__ inline f32x4 mfma16(bf16x8 a, bf16x8 b, f32x4 c) {
  return __builtin_amdgcn_mfma_f32_16x16x32_bf16(a, b, c, 0, 0, 0);
}
__device__ inline void gll16(const void* g, void* l) {
  __builtin_amdgcn_global_load_lds((gas_u32*)g, (las_u32*)l, 16, 0, 0);
}
#define VMCNT(n) asm volatile("s_waitcnt vmcnt(" #n ")" ::: "memory")

// ---- rope table: cos/sin[t][d], t<4096, d<64 ----
__global__ __launch_bounds__(256) void rope_kernel(float* __restrict__ cosT,
                                                   float* __restrict__ sinT) {
  int i = blockIdx.x * 256 + threadIdx.x;  // 262144
  int t = i >> 6, d = i & 63;
  float theta = powf(10000.f, -(float)d * (1.f / 64.f));
  float fr = (float)t * theta;
  cosT[i] = cosf(fr);
  sinT[i] = sinf(fr);
}

// ---- WT prep: [384][1024] bf16, PRE-SWIZZLED bytes within each 128B k-block:
// byte = ((k&63)*2) ^ ((n&7)<<4). Sections: [0..127]=Wq*scale, [128..255]=Wk,
// [256..383]=Wv. Q/K rows reordered so each wave's 64-col slice holds matched
// rope lo/hi pairs: row n: col = (n>>6)*32 + (n&31) + ((n>>5)&1)*64.
__global__ __launch_bounds__(256) void wtprep_kernel(const float* __restrict__ Wq,
                                                     const float* __restrict__ Wk,
                                                     const float* __restrict__ Wv,
                                                     char* __restrict__ WT) {
  int i = blockIdx.x * 256 + threadIdx.x;  // 384*1024
  int n = i >> 10, k = i & 1023;
  float v;
  if (n < 128) {
    int col = (n >> 6) * 32 + (n & 31) + ((n >> 5) & 1) * 64;
    v = Wq[(size_t)k * 128 + col] * 0.12751741656f;  // log2(e)/sqrt(128)
  } else if (n < 256) {
    int nk = n - 128;
    int col = (nk >> 6) * 32 + (nk & 31) + ((nk >> 5) & 1) * 64;
    v = Wk[(size_t)k * 128 + col];
  } else {
    v = Wv[(size_t)k * 128 + (n - 256)];
  }
  size_t off = (size_t)n * 2048 + (size_t)(k >> 6) * 128 + (((k & 63) * 2) ^ ((n & 7) << 4));
  *(short*)(WT + off) = f2bf(v);
}

// ---- projection GEMM (unchanged from round 9) ----
__global__ __launch_bounds__(256, 3) void gemm_fused(const float* __restrict__ x,
                                                     const char* __restrict__ WT,
                                                     const float* __restrict__ cosT,
                                                     const float* __restrict__ sinT,
                                                     short* __restrict__ Qb,
                                                     char* __restrict__ Kswz,
                                                     char* __restrict__ Vswz) {
  __shared__ __align__(16) char Al[2][8192];    // 64 rows x 64 k bf16, swizzled
  __shared__ __align__(16) char Bl[2][16384];   // 128 rows x 64 k bf16, pre-swz copy
  const int tid = threadIdx.x;
  const int w = tid >> 6, g = (tid >> 4) & 3, c = tid & 15;
  const int wr = w >> 1, wc = w & 1;
  const int swc = (c & 7) << 4;
  const int x8 = blockIdx.x & 7, jj0 = blockIdx.x >> 3;  // jj0: 0..95
  const int nb = jj0 % 3, tl = jj0 / 3;                  // 32 trios per XCD
  const int mt = x8 * 32 + tl;
  const int m0 = mt * 64;
  const char* WTB = WT + (size_t)nb * 128 * 2048;
  const int arow = tid >> 2, apart = tid & 3;
  const int sws = (arow & 7) << 4;
  const float* xsrc = x + (size_t)(m0 + arow) * 1024 + apart * 16;

  f32x4 acc[2][4];
#pragma unroll
  for (int mf = 0; mf < 2; mf++)
#pragma unroll
    for (int n = 0; n < 4; n++) acc[mf][n] = (f32x4){0.f, 0.f, 0.f, 0.f};

  float4 areg[4];
  auto ALOAD = [&](int ki) {
#pragma unroll
    for (int t = 0; t < 4; t++) areg[t] = *(const float4*)(xsrc + (size_t)ki * 64 + t * 4);
  };
  auto AWRITE = [&](int buf) {
    bf16x8 v0 = {f2bf(areg[0].x), f2bf(areg[0].y), f2bf(areg[0].z), f2bf(areg[0].w),
                 f2bf(areg[1].x), f2bf(areg[1].y), f2bf(areg[1].z), f2bf(areg[1].w)};
    bf16x8 v1 = {f2bf(areg[2].x), f2bf(areg[2].y), f2bf(areg[2].z), f2bf(areg[2].w),
                 f2bf(areg[3].x), f2bf(areg[3].y), f2bf(areg[3].z), f2bf(areg[3].w)};
    *(bf16x8*)(Al[buf] + arow * 128 + ((apart * 32) ^ sws)) = v0;
    *(bf16x8*)(Al[buf] + arow * 128 + ((apart * 32 + 16) ^ sws)) = v1;
  };
  auto BSTAGE = [&](int ki, int buf) {
#pragma unroll
    for (int i2 = 0; i2 < 4; i2++) {
      int j = tid + 256 * i2;
      gll16(WTB + (size_t)(j >> 3) * 2048 + ki * 128 + (j & 7) * 16, Bl[buf] + j * 16);
    }
  };
  auto COMPUTE = [&](int buf) {
#pragma unroll
    for (int kc = 0; kc < 2; kc++) {
      bf16x8 af[2], bfr[4];
#pragma unroll
      for (int mf = 0; mf < 2; mf++)
        af[mf] = *(const bf16x8*)(Al[buf] + (wr * 32 + mf * 16 + c) * 128 + ((kc * 64 + 16 * g) ^ swc));
#pragma unroll
      for (int n0 = 0; n0 < 4; n0++)
        bfr[n0] = *(const bf16x8*)(Bl[buf] + (wc * 64 + n0 * 16 + c) * 128 + ((kc * 64 + 16 * g) ^ swc));
#pragma unroll
      for (int mf = 0; mf < 2; mf++)
#pragma unroll
        for (int n0 = 0; n0 < 4; n0++) acc[mf][n0] = mfma16(af[mf], bfr[n0], acc[mf][n0]);
    }
  };

  ALOAD(0);
  AWRITE(0);
  BSTAGE(0, 0);
  ALOAD(1);
  __syncthreads();
#pragma unroll 1
  for (int ki = 0; ki < 16; ki++) {
    const int cur = ki & 1;
    if (ki + 1 < 16) {
      AWRITE(cur ^ 1);
      BSTAGE(ki + 1, cur ^ 1);
      ALOAD(ki + 2 < 16 ? ki + 2 : 15);
    }
    COMPUTE(cur);
    __syncthreads();
  }

  if (nb == 0) {
#pragma unroll
    for (int mf = 0; mf < 2; mf++)
#pragma unroll
      for (int r = 0; r < 4; r++) {
        int mm = m0 + wr * 32 + mf * 16 + 4 * g + r;
        int t = mm & 4095;
#pragma unroll
        for (int n0 = 0; n0 < 2; n0++) {
          int d = wc * 32 + n0 * 16 + c;
          float co = cosT[t * 64 + d], si = sinT[t * 64 + d];
          float lo = acc[mf][n0][r], hi = acc[mf][n0 + 2][r];
          Qb[(size_t)mm * 128 + d] = f2bf(lo * co - hi * si);
          Qb[(size_t)mm * 128 + d + 64] = f2bf(hi * co + lo * si);
        }
      }
  } else if (nb == 1) {
#pragma unroll
    for (int mf = 0; mf < 2; mf++) {
      int kp = ((m0 + wr * 32 + mf * 16) >> 2) + g;
      int kpos = kp & 1023;
      int ksw = (kp & 7) << 4;
      char* kb2 = Kswz + (size_t)kp * 256;
#pragma unroll
      for (int n0 = 0; n0 < 2; n0++) {
        int d = wc * 32 + n0 * 16 + c;
        float lo = 0.25f * (acc[mf][n0][0] + acc[mf][n0][1] + acc[mf][n0][2] + acc[mf][n0][3]);
        float hi = 0.25f * (acc[mf][n0 + 2][0] + acc[mf][n0 + 2][1] + acc[mf][n0 + 2][2] + acc[mf][n0 + 2][3]);
        float co = cosT[kpos * 64 + d], si = sinT[kpos * 64 + d];
        *(short*)(kb2 + ((d * 2) ^ ksw)) = f2bf(lo * co - hi * si);
        *(short*)(kb2 + (((d + 64) * 2) ^ ksw)) = f2bf(hi * co + lo * si);
      }
    }
  } else {
    // V: pool over r, store [b][subtile32][64 r][144B]: byte = r*144 + h*64 + kk*2
#pragma unroll
    for (int mf = 0; mf < 2; mf++) {
      int kp = ((m0 + wr * 32 + mf * 16) >> 2) + g;
      int kpos = kp & 1023, bb = kp >> 10;
#pragma unroll
      for (int n0 = 0; n0 < 4; n0++) {
        int r = n0 * 16 + c;         // d = wc*64 + r, h = wc
        float vp = 0.25f * (acc[mf][n0][0] + acc[mf][n0][1] + acc[mf][n0][2] + acc[mf][n0][3]);
        size_t off = (size_t)(bb * 32 + (kpos >> 5)) * 9216 + r * 144 + wc * 64 +
                     (kpos & 31) * 2;
        *(short*)(Vswz + off) = f2bf(vp);
      }
    }
  }
}

// ---- fused two-branch flash attention, mirror-paired block, KVBLK=64 ----
// grid 512, 256 thr = 4 waves: w0,w1 causal rows [q0b, q0b+32); w2,w3 unmasked
// mirror rows; combine through LDS; swapped QK^T (lane-local softmax).
// 16 fat tiles of 64 keys (vs r8/r9's 32 thin tiles): halves the per-tile
// barrier/waitcnt serial chain count — the measured limiter (3300 cy/tile at
// only ~77 cy MFMA). LDS 78.8 KB -> 2 blocks/CU (grid caps residency anyway).
__global__ __launch_bounds__(256, 2) void attn_kernel(const short* __restrict__ Qb,
                                                      const char* __restrict__ Kswz,
                                                      const char* __restrict__ Vswz,
                                                      const float* __restrict__ alphap,
                                                      float* __restrict__ out) {
  __shared__ __align__(16) char lds[32768 + 36864 + 4 * 2304];  // K + V + P = 78848
  char* Kl = lds;            // 2 bufs x [64 keys x 256B] (pre-swz rows)
  char* Vl = lds + 32768;    // 2 bufs x [2 subtiles x [64 r][144B]] = 2 x 18432
  const int tid = threadIdx.x;
  const int w = tid >> 6, g = (tid >> 4) & 3, c = tid & 15;
  char* Pl = lds + 69632 + w * 2304;  // 16 q-rows x 144B (64 keys x 2B + pad)
  const int blk = blockIdx.x;
  const int b = blk >> 7, qc = blk & 127;
  const int q0b = qc * 32;
  const bool isC = (w < 2);
  const int qbase = isC ? (q0b + w * 16) : (4064 - q0b + (w - 2) * 16);
  const int myq = qbase + c;
  const int tile_b = qbase >> 8;  // boundary 64-key tile for this wave
  const int swc = (c & 7) << 4;

  bf16x8 qf[4];
  {
    const short* qr = Qb + ((size_t)b * T_ + myq) * 128;
#pragma unroll
    for (int kc = 0; kc < 4; kc++) qf[kc] = *(const bf16x8*)(qr + kc * 32 + 8 * g);
  }
  f32x4 acc[8];
#pragma unroll
  for (int n = 0; n < 8; n++) acc[n] = (f32x4){0.f, 0.f, 0.f, 0.f};
  float m = -1e30f, l = 0.f;

  const char* kbB = Kswz + (size_t)b * 262144;
  const char* vbB = Vswz + (size_t)b * 294912;

  // stage one 64-key tile: K 16 KB (4 gll/thr) + V 18 KB (4 gll/thr + half tail)
  auto STG = [&](int tg, char* kd, char* vd) {
    const char* kb = kbB + (size_t)tg * 16384;
    const char* vb = vbB + (size_t)tg * 18432;
#pragma unroll
    for (int j = 0; j < 4; j++) gll16(kb + j * 4096 + tid * 16, kd + j * 4096 + tid * 16);
#pragma unroll
    for (int j = 0; j < 4; j++) gll16(vb + j * 4096 + tid * 16, vd + j * 4096 + tid * 16);
    if (tid < 128) gll16(vb + 16384 + tid * 16, vd + 16384 + tid * 16);  // 2KB tail
  };

  STG(0, Kl, Vl);

#pragma unroll 1
  for (int tg = 0; tg < 16; tg++) {
    const int kcur = (tg & 1) * 16384;
    const int vcur = (tg & 1) * 18432;
    if (tg < 15) {
      STG(tg + 1, Kl + (16384 - kcur), Vl + (18432 - vcur));
      if (w < 2) { VMCNT(9); } else { VMCNT(8); }  // drain prev tile; keep newest
    } else {
      VMCNT(0);
    }
    __builtin_amdgcn_s_barrier();

    if (!isC || tg <= tile_b) {
      // QK^T swapped: s[n][r] = S[key = tg*64 + 16n + 4g + r][q = myq]
      f32x4 s[4];
#pragma unroll
      for (int n = 0; n < 4; n++) s[n] = (f32x4){0.f, 0.f, 0.f, 0.f};
#pragma unroll
      for (int kc = 0; kc < 4; kc++) {
#pragma unroll
        for (int n = 0; n < 4; n++) {
          bf16x8 kf = *(const bf16x8*)(Kl + kcur + (16 * n + c) * 256 + ((kc * 64 + 16 * g) ^ swc));
          s[n] = mfma16(kf, qf[kc], s[n]);
        }
      }
      if (isC && tg == tile_b) {  // boundary mask
        int klim = (myq >> 2) - tg * 64;
#pragma unroll
        for (int n = 0; n < 4; n++)
#pragma unroll
          for (int r = 0; r < 4; r++)
            if (16 * n + 4 * g + r > klim) s[n][r] = -3.0e38f;
      }
      float tm = fmaxf(fmaxf(fmaxf(s[0][0], s[0][1]), fmaxf(s[0][2], s[0][3])),
                       fmaxf(fmaxf(s[1][0], s[1][1]), fmaxf(s[1][2], s[1][3])));
      tm = fmaxf(tm, fmaxf(fmaxf(fmaxf(s[2][0], s[2][1]), fmaxf(s[2][2], s[2][3])),
                           fmaxf(fmaxf(s[3][0], s[3][1]), fmaxf(s[3][2], s[3][3]))));
      tm = fmaxf(tm, __shfl_xor(tm, 16));
      tm = fmaxf(tm, __shfl_xor(tm, 32));
      if (__any(tm > m + 8.f)) {  // defer-max
        float mn = fmaxf(m, tm);
        float sc = __builtin_amdgcn_exp2f(m - mn);
        m = mn;
        l *= sc;
        float s0 = __shfl(sc, 4 * g), s1 = __shfl(sc, 4 * g + 1);
        float s2 = __shfl(sc, 4 * g + 2), s3 = __shfl(sc, 4 * g + 3);
        f32x4 scv = {s0, s1, s2, s3};
#pragma unroll
        for (int n0 = 0; n0 < 8; n0++) acc[n0] *= scv;
      }
      float rsum = 0.f;
#pragma unroll
      for (int n = 0; n < 4; n++) {
        float p0 = __builtin_amdgcn_exp2f(s[n][0] - m);
        float p1 = __builtin_amdgcn_exp2f(s[n][1] - m);
        float p2 = __builtin_amdgcn_exp2f(s[n][2] - m);
        float p3 = __builtin_amdgcn_exp2f(s[n][3] - m);
        rsum += (p0 + p1) + (p2 + p3);
        s16x4 pk = {f2bf(p0), f2bf(p1), f2bf(p2), f2bf(p3)};
        *(s16x4*)(Pl + c * 144 + 32 * n + 8 * g) = pk;  // keys 16n+4g..+3
      }
      rsum += __shfl_xor(rsum, 16);
      rsum += __shfl_xor(rsum, 32);
      l += rsum;
#pragma unroll
      for (int kc = 0; kc < 2; kc++) {
        bf16x8 pf = *(const bf16x8*)(Pl + c * 144 + 64 * kc + 16 * g);  // keys 32kc+8g..+7
#pragma unroll
        for (int n0 = 0; n0 < 8; n0++) {
          // V subtile kc, row r = (n0&3)*16 + c, half h = n0>>2, keys 8g..8g+7
          bf16x8 v0 = *(const bf16x8*)(Vl + vcur + kc * 9216 +
                                       ((n0 & 3) * 16 + c) * 144 + (n0 >> 2) * 64 + 16 * g);
          acc[n0] = mfma16(pf, v0, acc[n0]);
        }
      }
    }
    __builtin_amdgcn_s_barrier();
  }

  // epilogue: per-output-row 1/l, exchange U through LDS, combine, write
  float lr0 = __shfl(l, 4 * g), lr1 = __shfl(l, 4 * g + 1);
  float lr2 = __shfl(l, 4 * g + 2), lr3 = __shfl(l, 4 * g + 3);
  f32x4 linv = {1.f / lr0, 1.f / lr1, 1.f / lr2, 1.f / lr3};
  float* Ul = (float*)lds;  // [32][132] overlay = 16.9 KB (all K/V reads done)
  if (!isC) {
#pragma unroll
    for (int n0 = 0; n0 < 8; n0++)
#pragma unroll
      for (int r = 0; r < 4; r++) {
        int urow = 31 - (16 * (w - 2) + 4 * g + r);
        Ul[urow * 132 + n0 * 16 + c] = acc[n0][r] * linv[r];
      }
  }
  __syncthreads();
  if (isC) {
    float alpha = 1.f / (1.f + expf(-alphap[0]));
    float oma = 1.f - alpha;
#pragma unroll
    for (int n0 = 0; n0 < 8; n0++)
#pragma unroll
      for (int r = 0; r < 4; r++) {
        int j = 16 * w + 4 * g + r;
        float uvv = Ul[j * 132 + n0 * 16 + c];
        out[((size_t)b * T_ + q0b + j) * 128 + n0 * 16 + c] =
            alpha * acc[n0][r] * linv[r] + oma * uvv;
      }
  }
}

extern "C" void kernel_launch(void* const* d_in, const int* in_sizes, int n_in,
                              void* d_out, int out_size, void* d_ws, size_t ws_size,
                              hipStream_t stream) {
  const float* x = (const float*)d_in[0];
  const float* Wq = (const float*)d_in[1];
  const float* Wk = (const float*)d_in[2];
  const float* Wv = (const float*)d_in[3];
  const float* falpha = (const float*)d_in[9];
  char* ws = (char*)d_ws;
  float* cosT = (float*)(ws);                  // 1 MB
  float* sinT = (float*)(ws + 1048576);        // 1 MB
  char* WT = ws + 2097152;                     // 768 KB  [384][1024] bf16, pre-swizzled
  short* Qb = (short*)(ws + 2883584);          // 4 MB    roped+scaled Q bf16
  char* Kswz = ws + 7077888;                   // 1 MB    roped pooled K bf16, swizzled
  char* Vswz = ws + 8126464;                   // 1.18 MB pooled V, [b][subtile32][64r][144B]

  rope_kernel<<<1024, 256, 0, stream>>>(cosT, sinT);
  wtprep_kernel<<<1536, 256, 0, stream>>>(Wq, Wk, Wv, WT);
  gemm_fused<<<768, 256, 0, stream>>>(x, WT, cosT, sinT, Qb, Kswz, Vswz);
  attn_kernel<<<512, 256, 0, stream>>>(Qb, Kswz, Vswz, falpha, (float*)d_out);
}

// Round 11
// 73.344 us; speedup vs baseline: 1.0750x; 1.0223x over previous
//
#include <hip/hip_runtime.h>
#include <hip/hip_bf16.h>
#include <math.h>

// FluxHead: B=4, T=4096, D_MODEL=1024, HEAD_DIM=128, STRIDE=4, Tk=1024, CAUSAL
// Exact-math simplifications:
//  - spectral gate adds a per-(b,q) scalar to logits -> softmax-invariant -> skipped
//  - reverse branch == unmasked forward attention, output read at mirror row
//  - pooling commutes with K/V projection -> pooled in GEMM epilogue (lane-local)
//  - log2e/SCALE folded into Wq -> softmax in exp2 units

#define T_ 4096
#define TK_ 1024

typedef __attribute__((ext_vector_type(8))) short bf16x8;
typedef __attribute__((ext_vector_type(4))) float f32x4;
typedef __attribute__((ext_vector_type(4))) short s16x4;
typedef __attribute__((address_space(1))) unsigned int gas_u32;
typedef __attribute__((address_space(3))) unsigned int las_u32;

__device__ inline short f2bf(float f) {
  unsigned u = __builtin_bit_cast(unsigned, f);
  u = (u + 0x7FFFu + ((u >> 16) & 1u)) >> 16;
  return (short)u;
}
__device__ inline f32x4 mfma16(bf16x8 a, bf16x8 b, f32x4 c) {
  return __builtin_amdgcn_mfma_f32_16x16x32_bf16(a, b, c, 0, 0, 0);
}
__device__ inline void gll16(const void* g, void* l) {
  __builtin_amdgcn_global_load_lds((gas_u32*)g, (las_u32*)l, 16, 0, 0);
}
#define VMCNT(n) asm volatile("s_waitcnt vmcnt(" #n ")" ::: "memory")
#define LGKM0() asm volatile("s_waitcnt lgkmcnt(0)" ::: "memory")

// ---- rope table: cos/sin[t][d], t<4096, d<64 ----
__global__ __launch_bounds__(256) void rope_kernel(float* __restrict__ cosT,
                                                   float* __restrict__ sinT) {
  int i = blockIdx.x * 256 + threadIdx.x;  // 262144
  int t = i >> 6, d = i & 63;
  float theta = powf(10000.f, -(float)d * (1.f / 64.f));
  float fr = (float)t * theta;
  cosT[i] = cosf(fr);
  sinT[i] = sinf(fr);
}

// ---- WT prep: [384][1024] bf16, PRE-SWIZZLED bytes within each 128B k-block:
// byte = ((k&63)*2) ^ ((n&7)<<4). Sections: [0..127]=Wq*scale, [128..255]=Wk,
// [256..383]=Wv. Q/K rows reordered so each wave's 64-col slice holds matched
// rope lo/hi pairs: row n: col = (n>>6)*32 + (n&31) + ((n>>5)&1)*64.
__global__ __launch_bounds__(256) void wtprep_kernel(const float* __restrict__ Wq,
                                                     const float* __restrict__ Wk,
                                                     const float* __restrict__ Wv,
                                                     char* __restrict__ WT) {
  int i = blockIdx.x * 256 + threadIdx.x;  // 384*1024
  int n = i >> 10, k = i & 1023;
  float v;
  if (n < 128) {
    int col = (n >> 6) * 32 + (n & 31) + ((n >> 5) & 1) * 64;
    v = Wq[(size_t)k * 128 + col] * 0.12751741656f;  // log2(e)/sqrt(128)
  } else if (n < 256) {
    int nk = n - 128;
    int col = (nk >> 6) * 32 + (nk & 31) + ((nk >> 5) & 1) * 64;
    v = Wk[(size_t)k * 128 + col];
  } else {
    v = Wv[(size_t)k * 128 + (n - 256)];
  }
  size_t off = (size_t)n * 2048 + (size_t)(k >> 6) * 128 + (((k & 63) * 2) ^ ((n & 7) << 4));
  *(short*)(WT + off) = f2bf(v);
}

// ---- projection GEMM: grid 768 = 8 XCD x (32 M-tiles x 3 N-blocks).
// Counted-vmcnt pipeline: raw s_barrier, VMCNT(4) keeps the (provably newest,
// not-yet-needed) x-prefetch in flight across barriers; x prefetch distance 3
// (ring areg[3], full unroll -> static indices). sched_barrier(0) pins ALOAD
// after BSTAGE so the VMCNT(4) invariant holds under compiler scheduling.
__global__ __launch_bounds__(256, 3) void gemm_fused(const float* __restrict__ x,
                                                     const char* __restrict__ WT,
                                                     const float* __restrict__ cosT,
                                                     const float* __restrict__ sinT,
                                                     short* __restrict__ Qb,
                                                     char* __restrict__ Kswz,
                                                     char* __restrict__ Vswz) {
  __shared__ __align__(16) char Al[2][8192];    // 64 rows x 64 k bf16, swizzled
  __shared__ __align__(16) char Bl[2][16384];   // 128 rows x 64 k bf16, pre-swz copy
  const int tid = threadIdx.x;
  const int w = tid >> 6, g = (tid >> 4) & 3, c = tid & 15;
  const int wr = w >> 1, wc = w & 1;
  const int swc = (c & 7) << 4;
  const int x8 = blockIdx.x & 7, jj0 = blockIdx.x >> 3;  // jj0: 0..95
  const int nb = jj0 % 3, tl = jj0 / 3;                  // 32 trios per XCD
  const int mt = x8 * 32 + tl;
  const int m0 = mt * 64;
  const char* WTB = WT + (size_t)nb * 128 * 2048;
  const int arow = tid >> 2, apart = tid & 3;
  const int sws = (arow & 7) << 4;
  const float* xsrc = x + (size_t)(m0 + arow) * 1024 + apart * 16;

  f32x4 acc[2][4];
#pragma unroll
  for (int mf = 0; mf < 2; mf++)
#pragma unroll
    for (int n = 0; n < 4; n++) acc[mf][n] = (f32x4){0.f, 0.f, 0.f, 0.f};

  float4 areg[3][4];
  auto ALOAD = [&](int slot, int ki) {
#pragma unroll
    for (int t = 0; t < 4; t++)
      areg[slot][t] = *(const float4*)(xsrc + (size_t)ki * 64 + t * 4);
  };
  auto AWRITE = [&](int buf, int slot) {
    bf16x8 v0 = {f2bf(areg[slot][0].x), f2bf(areg[slot][0].y), f2bf(areg[slot][0].z), f2bf(areg[slot][0].w),
                 f2bf(areg[slot][1].x), f2bf(areg[slot][1].y), f2bf(areg[slot][1].z), f2bf(areg[slot][1].w)};
    bf16x8 v1 = {f2bf(areg[slot][2].x), f2bf(areg[slot][2].y), f2bf(areg[slot][2].z), f2bf(areg[slot][2].w),
                 f2bf(areg[slot][3].x), f2bf(areg[slot][3].y), f2bf(areg[slot][3].z), f2bf(areg[slot][3].w)};
    *(bf16x8*)(Al[buf] + arow * 128 + ((apart * 32) ^ sws)) = v0;
    *(bf16x8*)(Al[buf] + arow * 128 + ((apart * 32 + 16) ^ sws)) = v1;
  };
  auto BSTAGE = [&](int ki, int buf) {
#pragma unroll
    for (int i2 = 0; i2 < 4; i2++) {
      int j = tid + 256 * i2;
      gll16(WTB + (size_t)(j >> 3) * 2048 + ki * 128 + (j & 7) * 16, Bl[buf] + j * 16);
    }
  };
  auto COMPUTE = [&](int buf) {
#pragma unroll
    for (int kc = 0; kc < 2; kc++) {
      bf16x8 af[2], bfr[4];
#pragma unroll
      for (int mf = 0; mf < 2; mf++)
        af[mf] = *(const bf16x8*)(Al[buf] + (wr * 32 + mf * 16 + c) * 128 + ((kc * 64 + 16 * g) ^ swc));
#pragma unroll
      for (int n0 = 0; n0 < 4; n0++)
        bfr[n0] = *(const bf16x8*)(Bl[buf] + (wc * 64 + n0 * 16 + c) * 128 + ((kc * 64 + 16 * g) ^ swc));
#pragma unroll
      for (int mf = 0; mf < 2; mf++)
#pragma unroll
        for (int n0 = 0; n0 < 4; n0++) acc[mf][n0] = mfma16(af[mf], bfr[n0], acc[mf][n0]);
    }
  };

  // prologue: x0..x2 -> regs; tile 0 -> buf0; full drain once
  ALOAD(0, 0);
  ALOAD(1, 1);
  ALOAD(2, 2);
  AWRITE(0, 0);
  BSTAGE(0, 0);
  VMCNT(0);
  LGKM0();
  __builtin_amdgcn_s_barrier();
#pragma unroll
  for (int ki = 0; ki < 16; ki++) {
    const int cur = ki & 1;
    if (ki + 1 < 16) {
      BSTAGE(ki + 1, cur ^ 1);            // W(ki+1) glls (oldest group at the wait)
      AWRITE(cur ^ 1, (ki + 1) % 3);      // x(ki+1) -> LDS (auto-wait: loaded 2-3 iters ago)
      __builtin_amdgcn_sched_barrier(0);  // pin: ALOAD must issue AFTER BSTAGE
      if (ki + 3 < 16) ALOAD((ki + 3) % 3, ki + 3);
      __builtin_amdgcn_sched_barrier(0);
    }
    COMPUTE(cur);
    if (ki + 3 < 16) { VMCNT(4); } else { VMCNT(0); }  // keep only newest ALOADs in flight
    LGKM0();
    __builtin_amdgcn_s_barrier();
  }

  // ---- epilogue: acc[mf][n0][r] = C[m0 + wr*32 + mf*16 + 4g + r][wc*64 + n0*16 + c]
  if (nb == 0) {
#pragma unroll
    for (int mf = 0; mf < 2; mf++)
#pragma unroll
      for (int r = 0; r < 4; r++) {
        int mm = m0 + wr * 32 + mf * 16 + 4 * g + r;
        int t = mm & 4095;
#pragma unroll
        for (int n0 = 0; n0 < 2; n0++) {
          int d = wc * 32 + n0 * 16 + c;
          float co = cosT[t * 64 + d], si = sinT[t * 64 + d];
          float lo = acc[mf][n0][r], hi = acc[mf][n0 + 2][r];
          Qb[(size_t)mm * 128 + d] = f2bf(lo * co - hi * si);
          Qb[(size_t)mm * 128 + d + 64] = f2bf(hi * co + lo * si);
        }
      }
  } else if (nb == 1) {
#pragma unroll
    for (int mf = 0; mf < 2; mf++) {
      int kp = ((m0 + wr * 32 + mf * 16) >> 2) + g;
      int kpos = kp & 1023;
      int ksw = (kp & 7) << 4;
      char* kb2 = Kswz + (size_t)kp * 256;
#pragma unroll
      for (int n0 = 0; n0 < 2; n0++) {
        int d = wc * 32 + n0 * 16 + c;
        float lo = 0.25f * (acc[mf][n0][0] + acc[mf][n0][1] + acc[mf][n0][2] + acc[mf][n0][3]);
        float hi = 0.25f * (acc[mf][n0 + 2][0] + acc[mf][n0 + 2][1] + acc[mf][n0 + 2][2] + acc[mf][n0 + 2][3]);
        float co = cosT[kpos * 64 + d], si = sinT[kpos * 64 + d];
        *(short*)(kb2 + ((d * 2) ^ ksw)) = f2bf(lo * co - hi * si);
        *(short*)(kb2 + (((d + 64) * 2) ^ ksw)) = f2bf(hi * co + lo * si);
      }
    }
  } else {
    // V: pool over r, store [b][subtile32][64 r][144B]: byte = r*144 + h*64 + kk*2
#pragma unroll
    for (int mf = 0; mf < 2; mf++) {
      int kp = ((m0 + wr * 32 + mf * 16) >> 2) + g;
      int kpos = kp & 1023, bb = kp >> 10;
#pragma unroll
      for (int n0 = 0; n0 < 4; n0++) {
        int r = n0 * 16 + c;         // d = wc*64 + r, h = wc
        float vp = 0.25f * (acc[mf][n0][0] + acc[mf][n0][1] + acc[mf][n0][2] + acc[mf][n0][3]);
        size_t off = (size_t)(bb * 32 + (kpos >> 5)) * 9216 + r * 144 + wc * 64 +
                     (kpos & 31) * 2;
        *(short*)(Vswz + off) = f2bf(vp);
      }
    }
  }
}

// ---- fused two-branch flash attention, mirror-paired block, KVBLK=64 ----
// [UNCHANGED from round 10]
__global__ __launch_bounds__(256, 2) void attn_kernel(const short* __restrict__ Qb,
                                                      const char* __restrict__ Kswz,
                                                      const char* __restrict__ Vswz,
                                                      const float* __restrict__ alphap,
                                                      float* __restrict__ out) {
  __shared__ __align__(16) char lds[32768 + 36864 + 4 * 2304];  // K + V + P = 78848
  char* Kl = lds;            // 2 bufs x [64 keys x 256B] (pre-swz rows)
  char* Vl = lds + 32768;    // 2 bufs x [2 subtiles x [64 r][144B]] = 2 x 18432
  const int tid = threadIdx.x;
  const int w = tid >> 6, g = (tid >> 4) & 3, c = tid & 15;
  char* Pl = lds + 69632 + w * 2304;  // 16 q-rows x 144B (64 keys x 2B + pad)
  const int blk = blockIdx.x;
  const int b = blk >> 7, qc = blk & 127;
  const int q0b = qc * 32;
  const bool isC = (w < 2);
  const int qbase = isC ? (q0b + w * 16) : (4064 - q0b + (w - 2) * 16);
  const int myq = qbase + c;
  const int tile_b = qbase >> 8;  // boundary 64-key tile for this wave
  const int swc = (c & 7) << 4;

  bf16x8 qf[4];
  {
    const short* qr = Qb + ((size_t)b * T_ + myq) * 128;
#pragma unroll
    for (int kc = 0; kc < 4; kc++) qf[kc] = *(const bf16x8*)(qr + kc * 32 + 8 * g);
  }
  f32x4 acc[8];
#pragma unroll
  for (int n = 0; n < 8; n++) acc[n] = (f32x4){0.f, 0.f, 0.f, 0.f};
  float m = -1e30f, l = 0.f;

  const char* kbB = Kswz + (size_t)b * 262144;
  const char* vbB = Vswz + (size_t)b * 294912;

  auto STG = [&](int tg, char* kd, char* vd) {
    const char* kb = kbB + (size_t)tg * 16384;
    const char* vb = vbB + (size_t)tg * 18432;
#pragma unroll
    for (int j = 0; j < 4; j++) gll16(kb + j * 4096 + tid * 16, kd + j * 4096 + tid * 16);
#pragma unroll
    for (int j = 0; j < 4; j++) gll16(vb + j * 4096 + tid * 16, vd + j * 4096 + tid * 16);
    if (tid < 128) gll16(vb + 16384 + tid * 16, vd + 16384 + tid * 16);  // 2KB tail
  };

  STG(0, Kl, Vl);

#pragma unroll 1
  for (int tg = 0; tg < 16; tg++) {
    const int kcur = (tg & 1) * 16384;
    const int vcur = (tg & 1) * 18432;
    if (tg < 15) {
      STG(tg + 1, Kl + (16384 - kcur), Vl + (18432 - vcur));
      if (w < 2) { VMCNT(9); } else { VMCNT(8); }  // drain prev tile; keep newest
    } else {
      VMCNT(0);
    }
    __builtin_amdgcn_s_barrier();

    if (!isC || tg <= tile_b) {
      // QK^T swapped: s[n][r] = S[key = tg*64 + 16n + 4g + r][q = myq]
      f32x4 s[4];
#pragma unroll
      for (int n = 0; n < 4; n++) s[n] = (f32x4){0.f, 0.f, 0.f, 0.f};
#pragma unroll
      for (int kc = 0; kc < 4; kc++) {
#pragma unroll
        for (int n = 0; n < 4; n++) {
          bf16x8 kf = *(const bf16x8*)(Kl + kcur + (16 * n + c) * 256 + ((kc * 64 + 16 * g) ^ swc));
          s[n] = mfma16(kf, qf[kc], s[n]);
        }
      }
      if (isC && tg == tile_b) {  // boundary mask
        int klim = (myq >> 2) - tg * 64;
#pragma unroll
        for (int n = 0; n < 4; n++)
#pragma unroll
          for (int r = 0; r < 4; r++)
            if (16 * n + 4 * g + r > klim) s[n][r] = -3.0e38f;
      }
      float tm = fmaxf(fmaxf(fmaxf(s[0][0], s[0][1]), fmaxf(s[0][2], s[0][3])),
                       fmaxf(fmaxf(s[1][0], s[1][1]), fmaxf(s[1][2], s[1][3])));
      tm = fmaxf(tm, fmaxf(fmaxf(fmaxf(s[2][0], s[2][1]), fmaxf(s[2][2], s[2][3])),
                           fmaxf(fmaxf(s[3][0], s[3][1]), fmaxf(s[3][2], s[3][3]))));
      tm = fmaxf(tm, __shfl_xor(tm, 16));
      tm = fmaxf(tm, __shfl_xor(tm, 32));
      if (__any(tm > m + 8.f)) {  // defer-max
        float mn = fmaxf(m, tm);
        float sc = __builtin_amdgcn_exp2f(m - mn);
        m = mn;
        l *= sc;
        float s0 = __shfl(sc, 4 * g), s1 = __shfl(sc, 4 * g + 1);
        float s2 = __shfl(sc, 4 * g + 2), s3 = __shfl(sc, 4 * g + 3);
        f32x4 scv = {s0, s1, s2, s3};
#pragma unroll
        for (int n0 = 0; n0 < 8; n0++) acc[n0] *= scv;
      }
      float rsum = 0.f;
#pragma unroll
      for (int n = 0; n < 4; n++) {
        float p0 = __builtin_amdgcn_exp2f(s[n][0] - m);
        float p1 = __builtin_amdgcn_exp2f(s[n][1] - m);
        float p2 = __builtin_amdgcn_exp2f(s[n][2] - m);
        float p3 = __builtin_amdgcn_exp2f(s[n][3] - m);
        rsum += (p0 + p1) + (p2 + p3);
        s16x4 pk = {f2bf(p0), f2bf(p1), f2bf(p2), f2bf(p3)};
        *(s16x4*)(Pl + c * 144 + 32 * n + 8 * g) = pk;  // keys 16n+4g..+3
      }
      rsum += __shfl_xor(rsum, 16);
      rsum += __shfl_xor(rsum, 32);
      l += rsum;
#pragma unroll
      for (int kc = 0; kc < 2; kc++) {
        bf16x8 pf = *(const bf16x8*)(Pl + c * 144 + 64 * kc + 16 * g);  // keys 32kc+8g..+7
#pragma unroll
        for (int n0 = 0; n0 < 8; n0++) {
          bf16x8 v0 = *(const bf16x8*)(Vl + vcur + kc * 9216 +
                                       ((n0 & 3) * 16 + c) * 144 + (n0 >> 2) * 64 + 16 * g);
          acc[n0] = mfma16(pf, v0, acc[n0]);
        }
      }
    }
    __builtin_amdgcn_s_barrier();
  }

  // epilogue: per-output-row 1/l, exchange U through LDS, combine, write
  float lr0 = __shfl(l, 4 * g), lr1 = __shfl(l, 4 * g + 1);
  float lr2 = __shfl(l, 4 * g + 2), lr3 = __shfl(l, 4 * g + 3);
  f32x4 linv = {1.f / lr0, 1.f / lr1, 1.f / lr2, 1.f / lr3};
  float* Ul = (float*)lds;  // [32][132] overlay = 16.9 KB (all K/V reads done)
  if (!isC) {
#pragma unroll
    for (int n0 = 0; n0 < 8; n0++)
#pragma unroll
      for (int r = 0; r < 4; r++) {
        int urow = 31 - (16 * (w - 2) + 4 * g + r);
        Ul[urow * 132 + n0 * 16 + c] = acc[n0][r] * linv[r];
      }
  }
  __syncthreads();
  if (isC) {
    float alpha = 1.f / (1.f + expf(-alphap[0]));
    float oma = 1.f - alpha;
#pragma unroll
    for (int n0 = 0; n0 < 8; n0++)
#pragma unroll
      for (int r = 0; r < 4; r++) {
        int j = 16 * w + 4 * g + r;
        float uvv = Ul[j * 132 + n0 * 16 + c];
        out[((size_t)b * T_ + q0b + j) * 128 + n0 * 16 + c] =
            alpha * acc[n0][r] * linv[r] + oma * uvv;
      }
  }
}

extern "C" void kernel_launch(void* const* d_in, const int* in_sizes, int n_in,
                              void* d_out, int out_size, void* d_ws, size_t ws_size,
                              hipStream_t stream) {
  const float* x = (const float*)d_in[0];
  const float* Wq = (const float*)d_in[1];
  const float* Wk = (const float*)d_in[2];
  const float* Wv = (const float*)d_in[3];
  const float* falpha = (const float*)d_in[9];
  char* ws = (char*)d_ws;
  float* cosT = (float*)(ws);                  // 1 MB
  float* sinT = (float*)(ws + 1048576);        // 1 MB
  char* WT = ws + 2097152;                     // 768 KB  [384][1024] bf16, pre-swizzled
  short* Qb = (short*)(ws + 2883584);          // 4 MB    roped+scaled Q bf16
  char* Kswz = ws + 7077888;                   // 1 MB    roped pooled K bf16, swizzled
  char* Vswz = ws + 8126464;                   // 1.18 MB pooled V, [b][subtile32][64r][144B]

  rope_kernel<<<1024, 256, 0, stream>>>(cosT, sinT);
  wtprep_kernel<<<1536, 256, 0, stream>>>(Wq, Wk, Wv, WT);
  gemm_fused<<<768, 256, 0, stream>>>(x, WT, cosT, sinT, Qb, Kswz, Vswz);
  attn_kernel<<<512, 256, 0, stream>>>(Qb, Kswz, Vswz, falpha, (float*)d_out);
}